// Round 1
// baseline (21451.582 us; speedup 1.0000x reference)
//
#include <hip/hip_runtime.h>

typedef unsigned short u16;
typedef unsigned int u32;
typedef __attribute__((ext_vector_type(8))) short bf16x8;
typedef __attribute__((ext_vector_type(4))) float f32x4;

#define SW(r) (((r) & 7) << 4)

__device__ __forceinline__ u16 f2bf(float f) {
  u32 x = __float_as_uint(f);
  x += 0x7fffu + ((x >> 16) & 1u);
  return (u16)(x >> 16);
}

union BF8 { bf16x8 v; u16 u[8]; };

__device__ __forceinline__ void gload_lds16(const void* g, void* l) {
  __builtin_amdgcn_global_load_lds(
      (const __attribute__((address_space(1))) u32*)g,
      (__attribute__((address_space(3))) u32*)l, 16, 0, 0);
}

__device__ __forceinline__ float fsigmoid(float x) { return 1.0f / (1.0f + __expf(-x)); }
__device__ __forceinline__ float ftanh(float x) {
  float a = fabsf(x);
  float t = __expf(-2.0f * a);
  float r = (1.0f - t) / (1.0f + t);
  return x < 0.0f ? -r : r;
}

// ---------------- prep: bf16 weight packs + padded concat input ----------------
__global__ void seqenc_prep(
    const float* __restrict__ state, const float* __restrict__ actions,
    const float* __restrict__ w0, const float* __restrict__ w1,
    const float* __restrict__ w2, const float* __restrict__ w3,
    const float* __restrict__ wih, const float* __restrict__ whh,
    const float* __restrict__ bih, const float* __restrict__ bhh,
    const float* __restrict__ wq, const float* __restrict__ wk, const float* __restrict__ wv,
    const float* __restrict__ bq, const float* __restrict__ bk, const float* __restrict__ bv,
    const float* __restrict__ wout,
    u16* __restrict__ Xpad, u16* __restrict__ Wcat, u16* __restrict__ Wqkv,
    u16* __restrict__ W0p, u16* __restrict__ W1b, u16* __restrict__ W2b,
    u16* __restrict__ W3b, u16* __restrict__ WoutB,
    float* __restrict__ bg, float* __restrict__ bqkv)
{
  const long NX = 25165824L, NC = 524288L, NQ = 196608L, N0P = 98304L;
  const long N1 = 262144L, N2 = 262144L, N3 = 131072L, NO = 65536L;
  const long NBG = 1024L, NBQ = 768L;
  const long TOT = NX + NC + NQ + N0P + N1 + N2 + N3 + NO + NBG + NBQ;
  for (long i = (long)blockIdx.x * blockDim.x + threadIdx.x; i < TOT;
       i += (long)gridDim.x * blockDim.x) {
    long j = i;
    if (j < NX) {  // Xpad[t*512 + b*8 + a][192] : [state(128) | actions(32) | 0(32)]
      long row = j / 192, col = j - row * 192;
      int t = (int)(row >> 9), r = (int)(row & 511);
      int b = r >> 3, a = r & 7;
      float v = 0.0f;
      if (col < 128) v = state[((long)(b * 256 + t)) * 128 + col];
      else if (col < 160) v = actions[(((long)(b * 256 + t)) * 8 + a) * 32 + (col - 128)];
      Xpad[j] = f2bf(v);
      continue;
    }
    j -= NX;
    if (j < NC) {  // Wcat[1024][512] = [w_ih | w_hh]
      long n = j >> 9, k = j & 511;
      float v = (k < 256) ? wih[n * 256 + k] : whh[n * 256 + (k - 256)];
      Wcat[j] = f2bf(v); continue;
    }
    j -= NC;
    if (j < NQ) {  // Wqkv[768][256]
      long n = j >> 8, k = j & 255;
      float v = (n < 256) ? wq[n * 256 + k] : (n < 512) ? wk[(n - 256) * 256 + k]
                                                        : wv[(n - 512) * 256 + k];
      Wqkv[j] = f2bf(v); continue;
    }
    j -= NQ;
    if (j < N0P) {  // W0p[512][192] zero-padded
      long n = j / 192, k = j - n * 192;
      W0p[j] = f2bf(k < 160 ? w0[n * 160 + k] : 0.0f); continue;
    }
    j -= N0P;
    if (j < N1) { W1b[j] = f2bf(w1[j]); continue; }
    j -= N1;
    if (j < N2) { W2b[j] = f2bf(w2[j]); continue; }
    j -= N2;
    if (j < N3) { W3b[j] = f2bf(w3[j]); continue; }
    j -= N3;
    if (j < NO) { WoutB[j] = f2bf(wout[j]); continue; }
    j -= NO;
    if (j < NBG) { bg[j] = bih[j] + bhh[j]; continue; }
    j -= NBG;
    bqkv[j] = (j < 256) ? bq[j] : (j < 512) ? bk[j - 256] : bv[j - 512];
  }
}

// ---------------- MLP GEMM: C[M][N] = act(A[M][K] @ B[N][K]^T + bias) ----------------
// 128x128 tile, BK=64, 4 waves, global_load_lds(16B) with pre-swizzled source.
__global__ __launch_bounds__(256) void seqenc_gemm(
    const u16* __restrict__ A, const u16* __restrict__ B,
    const float* __restrict__ bias, u16* __restrict__ C,
    int K, int N, int relu)
{
  __shared__ char As[16384];
  __shared__ char Bs[16384];
  const int tid = threadIdx.x;
  const int m0 = blockIdx.x * 128, n0 = blockIdx.y * 128;
  const int wid = tid >> 6, lane = tid & 63;
  const int wm = (wid >> 1) * 64, wn = (wid & 1) * 64;
  const int lr = lane & 15, kq = lane >> 4;
  f32x4 acc[4][4] = {};
  for (int kt = 0; kt < K; kt += 64) {
#pragma unroll
    for (int i2 = 0; i2 < 4; ++i2) {
      int q = i2 * 256 + tid;
      int r = q >> 3, cb = (q & 7) << 4;
      int scb = cb ^ SW(r);
      gload_lds16(A + (size_t)(m0 + r) * K + kt + (scb >> 1), As + q * 16);
      gload_lds16(B + (size_t)(n0 + r) * K + kt + (scb >> 1), Bs + q * 16);
    }
    __syncthreads();
#pragma unroll
    for (int ks = 0; ks < 2; ++ks) {
      bf16x8 af[4], bfr[4];
      int kb = ks * 64 + (kq << 4);
#pragma unroll
      for (int tt = 0; tt < 4; ++tt) {
        int ra = wm + tt * 16 + lr;
        af[tt] = *(const bf16x8*)(As + ra * 128 + (kb ^ SW(ra)));
        int rb = wn + tt * 16 + lr;
        bfr[tt] = *(const bf16x8*)(Bs + rb * 128 + (kb ^ SW(rb)));
      }
#pragma unroll
      for (int mt = 0; mt < 4; ++mt)
#pragma unroll
        for (int nt = 0; nt < 4; ++nt)
          acc[mt][nt] = __builtin_amdgcn_mfma_f32_16x16x32_bf16(af[mt], bfr[nt], acc[mt][nt], 0, 0, 0);
    }
    __syncthreads();
  }
#pragma unroll
  for (int mt = 0; mt < 4; ++mt) {
#pragma unroll
    for (int nt = 0; nt < 4; ++nt) {
      int gn = n0 + wn + nt * 16 + lr;
      float bv = bias[gn];
#pragma unroll
      for (int rr = 0; rr < 4; ++rr) {
        int gm = m0 + wm + mt * 16 + (kq << 2) + rr;
        float v = acc[mt][nt][rr] + bv;
        if (relu) v = fmaxf(v, 0.0f);
        C[(size_t)gm * N + gn] = f2bf(v);
      }
    }
  }
}

// ---------------- persistent recurrent kernel: 32 WGs x 512 thr, 16 rows each ----------------
__global__ __launch_bounds__(512) void seqenc_recurrent(
    const u16* __restrict__ X4, const u16* __restrict__ Wcat, const float* __restrict__ bg,
    const u16* __restrict__ Wqkv, const float* __restrict__ bqkv,
    u16* kbuf, u16* vt,
    const u16* __restrict__ WoutB, const float* __restrict__ bout,
    const float* __restrict__ h0g, const float* __restrict__ c0g,
    float* __restrict__ dout, unsigned* ctr)
{
  __shared__ float sc[16 * 256];       // c state (f32)
  __shared__ float sh[16 * 256];       // h state (f32)
  __shared__ float sosum[16 * 256];    // sum over t of h_post
  __shared__ char shb[16 * 512];       // h bf16, XOR-swizzled
  __shared__ char sqb[16 * 512];       // q bf16, XOR-swizzled
  __shared__ char spb[16 * 1024];      // P bf16, XOR-swizzled
  __shared__ float scratch[16 * 1028]; // gates / qkv / S staging

  const int tid = threadIdx.x;
  const int lane = tid & 63, wid = tid >> 6;
  const int lr = lane & 15, kq = lane >> 4;
  const int r0 = blockIdx.x * 16;

  {
    int r = tid >> 5, c8 = (tid & 31) * 8;
    BF8 hv;
#pragma unroll
    for (int j2 = 0; j2 < 8; ++j2) {
      float h = h0g[(size_t)(r0 + r) * 256 + c8 + j2];
      float c = c0g[(size_t)(r0 + r) * 256 + c8 + j2];
      sh[r * 256 + c8 + j2] = h;
      sc[r * 256 + c8 + j2] = c;
      sosum[r * 256 + c8 + j2] = 0.0f;
      hv.u[j2] = f2bf(h);
    }
    *(bf16x8*)(shb + r * 512 + ((c8 * 2) ^ SW(r))) = hv.v;
  }
  __syncthreads();

  for (int t = 0; t < 256; ++t) {
    // ---- Phase A: gates = [x_t | h] @ Wcat^T + bg  (K=512, N=1024) ----
    bf16x8 xf[8], hf[8];
#pragma unroll
    for (int ks = 0; ks < 8; ++ks) {
      xf[ks] = *(const bf16x8*)(X4 + (size_t)((t << 9) + r0 + lr) * 256 + ks * 32 + (kq << 3));
      hf[ks] = *(const bf16x8*)(shb + lr * 512 + ((ks * 64 + (kq << 4)) ^ SW(lr)));
    }
#pragma unroll
    for (int nt = 0; nt < 8; ++nt) {
      const int gn0 = wid * 128 + nt * 16;
      const u16* bp = Wcat + (size_t)(gn0 + lr) * 512 + (kq << 3);
      f32x4 a4 = {0.0f, 0.0f, 0.0f, 0.0f};
#pragma unroll
      for (int ks = 0; ks < 16; ++ks) {
        bf16x8 bw = *(const bf16x8*)(bp + ks * 32);
        a4 = __builtin_amdgcn_mfma_f32_16x16x32_bf16(ks < 8 ? xf[ks] : hf[ks - 8], bw, a4, 0, 0, 0);
      }
      float bb = bg[gn0 + lr];
#pragma unroll
      for (int rr = 0; rr < 4; ++rr)
        scratch[(kq * 4 + rr) * 1028 + gn0 + lr] = a4[rr] + bb;
    }
    __syncthreads();

    // ---- Phase B: LSTM pointwise update ----
    {
      int r = tid >> 5, c8 = (tid & 31) * 8;
      BF8 hv;
#pragma unroll
      for (int j2 = 0; j2 < 8; ++j2) {
        int c = c8 + j2;
        float iv = fsigmoid(scratch[r * 1028 + c]);
        float fv = fsigmoid(scratch[r * 1028 + 256 + c]);
        float gv = ftanh(scratch[r * 1028 + 512 + c]);
        float ov = fsigmoid(scratch[r * 1028 + 768 + c]);
        float cn = fv * sc[r * 256 + c] + iv * gv;
        float hn = ov * ftanh(cn);
        sc[r * 256 + c] = cn;
        sh[r * 256 + c] = hn;
        hv.u[j2] = f2bf(hn);
      }
      *(bf16x8*)(shb + r * 512 + ((c8 * 2) ^ SW(r))) = hv.v;
    }
    __syncthreads();

    // ---- Phase C: qkv = h_pre @ Wqkv^T + bqkv  (K=256, N=768) ----
    {
      bf16x8 hp[8];
#pragma unroll
      for (int ks = 0; ks < 8; ++ks)
        hp[ks] = *(const bf16x8*)(shb + lr * 512 + ((ks * 64 + (kq << 4)) ^ SW(lr)));
#pragma unroll
      for (int nt = 0; nt < 6; ++nt) {
        const int gn0 = wid * 96 + nt * 16;
        const u16* bp = Wqkv + (size_t)(gn0 + lr) * 256 + (kq << 3);
        f32x4 a4 = {0.0f, 0.0f, 0.0f, 0.0f};
#pragma unroll
        for (int ks = 0; ks < 8; ++ks)
          a4 = __builtin_amdgcn_mfma_f32_16x16x32_bf16(hp[ks], *(const bf16x8*)(bp + ks * 32), a4, 0, 0, 0);
        float bb = bqkv[gn0 + lr];
#pragma unroll
        for (int rr = 0; rr < 4; ++rr)
          scratch[(kq * 4 + rr) * 772 + gn0 + lr] = a4[rr] + bb;
      }
    }
    __syncthreads();

    // ---- Phase D: publish k (row-major) and v^T; q -> LDS ----
    {
      u16* kb = kbuf + (size_t)(t & 1) * 131072;
      u16* vb = vt + (size_t)(t & 1) * 131072;
      int r = tid >> 5, c8 = (tid & 31) * 8;
      BF8 qv, kv;
#pragma unroll
      for (int j2 = 0; j2 < 8; ++j2) {
        qv.u[j2] = f2bf(scratch[r * 772 + c8 + j2]);
        kv.u[j2] = f2bf(scratch[r * 772 + 256 + c8 + j2]);
      }
      *(bf16x8*)(sqb + r * 512 + ((c8 * 2) ^ SW(r))) = qv.v;
      *(bf16x8*)(kb + (size_t)(r0 + r) * 256 + c8) = kv.v;
      int d = tid >> 1, h8 = (tid & 1) * 8;
      BF8 vv;
#pragma unroll
      for (int j2 = 0; j2 < 8; ++j2)
        vv.u[j2] = f2bf(scratch[(h8 + j2) * 772 + 512 + d]);
      *(bf16x8*)(vb + (size_t)d * 512 + r0 + h8) = vv.v;
    }

    // ---- grid barrier (one per step) ----
    __syncthreads();
    if (tid == 0) {
      __threadfence();
      __hip_atomic_fetch_add(ctr, 1u, __ATOMIC_RELAXED, __HIP_MEMORY_SCOPE_AGENT);
      unsigned target = 32u * (unsigned)(t + 1);
      unsigned v = 0, sp = 0;
      do {
        v = __hip_atomic_load(ctr, __ATOMIC_RELAXED, __HIP_MEMORY_SCOPE_AGENT);
      } while (v < target && ++sp < 100000000u);
    }
    __syncthreads();
    __threadfence();

    // ---- Phase E: S = q @ k^T over all 512 keys, softmax ----
    {
      const u16* kb = kbuf + (size_t)(t & 1) * 131072;
      bf16x8 qf[8];
#pragma unroll
      for (int ks = 0; ks < 8; ++ks)
        qf[ks] = *(const bf16x8*)(sqb + lr * 512 + ((ks * 64 + (kq << 4)) ^ SW(lr)));
#pragma unroll
      for (int nt = 0; nt < 4; ++nt) {
        const int key0 = wid * 64 + nt * 16;
        const u16* bp = kb + (size_t)(key0 + lr) * 256 + (kq << 3);
        f32x4 a4 = {0.0f, 0.0f, 0.0f, 0.0f};
#pragma unroll
        for (int ks = 0; ks < 8; ++ks)
          a4 = __builtin_amdgcn_mfma_f32_16x16x32_bf16(qf[ks], *(const bf16x8*)(bp + ks * 32), a4, 0, 0, 0);
#pragma unroll
        for (int rr = 0; rr < 4; ++rr)
          scratch[(kq * 4 + rr) * 516 + key0 + lr] = a4[rr];
      }
    }
    __syncthreads();
    {
      int r = tid >> 5, l32 = tid & 31;
      float vals[16];
      float m = -3.4e38f;
#pragma unroll
      for (int j2 = 0; j2 < 16; ++j2) {
        vals[j2] = scratch[r * 516 + l32 + j2 * 32];
        m = fmaxf(m, vals[j2]);
      }
#pragma unroll
      for (int s2 = 16; s2 > 0; s2 >>= 1) m = fmaxf(m, __shfl_xor(m, s2, 32));
      float sum = 0.0f;
#pragma unroll
      for (int j2 = 0; j2 < 16; ++j2) {
        vals[j2] = __expf((vals[j2] - m) * 0.0625f);
        sum += vals[j2];
      }
#pragma unroll
      for (int s2 = 16; s2 > 0; s2 >>= 1) sum += __shfl_xor(sum, s2, 32);
      float inv = 1.0f / sum;
#pragma unroll
      for (int j2 = 0; j2 < 16; ++j2) {
        int c = l32 + j2 * 32;
        *(u16*)(spb + r * 1024 + ((c * 2) ^ SW(r))) = f2bf(vals[j2] * inv);
      }
    }
    __syncthreads();

    // ---- Phase F: h += P @ V (via v^T), accumulate outs ----
    {
      const u16* vb = vt + (size_t)(t & 1) * 131072;
      bf16x8 pf[16];
#pragma unroll
      for (int ks = 0; ks < 16; ++ks)
        pf[ks] = *(const bf16x8*)(spb + lr * 1024 + ((ks * 64 + (kq << 4)) ^ SW(lr)));
#pragma unroll
      for (int nt = 0; nt < 2; ++nt) {
        const int d0 = wid * 32 + nt * 16;
        const u16* bp = vb + (size_t)(d0 + lr) * 512 + (kq << 3);
        f32x4 a4 = {0.0f, 0.0f, 0.0f, 0.0f};
#pragma unroll
        for (int ks = 0; ks < 16; ++ks)
          a4 = __builtin_amdgcn_mfma_f32_16x16x32_bf16(pf[ks], *(const bf16x8*)(bp + ks * 32), a4, 0, 0, 0);
#pragma unroll
        for (int rr = 0; rr < 4; ++rr) {
          int row = kq * 4 + rr, col = d0 + lr;
          int idx = row * 256 + col;
          float hn = sh[idx] + a4[rr];
          sh[idx] = hn;
          sosum[idx] += hn;
          *(u16*)(shb + row * 512 + ((col * 2) ^ SW(row))) = f2bf(hn);
        }
      }
    }
    __syncthreads();
  }

  // ---- tail: out = (osum/256) @ Wout^T + bout ----
  {
    int r = tid >> 5, c8 = (tid & 31) * 8;
    BF8 ov;
#pragma unroll
    for (int j2 = 0; j2 < 8; ++j2)
      ov.u[j2] = f2bf(sosum[r * 256 + c8 + j2] * (1.0f / 256.0f));
    *(bf16x8*)(shb + r * 512 + ((c8 * 2) ^ SW(r))) = ov.v;
  }
  __syncthreads();
  {
    bf16x8 of[8];
#pragma unroll
    for (int ks = 0; ks < 8; ++ks)
      of[ks] = *(const bf16x8*)(shb + lr * 512 + ((ks * 64 + (kq << 4)) ^ SW(lr)));
#pragma unroll
    for (int nt = 0; nt < 2; ++nt) {
      const int gn = wid * 32 + nt * 16 + lr;
      const u16* bp = WoutB + (size_t)gn * 256 + (kq << 3);
      f32x4 a4 = {0.0f, 0.0f, 0.0f, 0.0f};
#pragma unroll
      for (int ks = 0; ks < 8; ++ks)
        a4 = __builtin_amdgcn_mfma_f32_16x16x32_bf16(of[ks], *(const bf16x8*)(bp + ks * 32), a4, 0, 0, 0);
      float bb = bout[gn];
#pragma unroll
      for (int rr = 0; rr < 4; ++rr)
        dout[(size_t)(r0 + kq * 4 + rr) * 256 + gn] = a4[rr] + bb;
    }
  }
}

extern "C" void kernel_launch(void* const* d_in, const int* in_sizes, int n_in,
                              void* d_out, int out_size, void* d_ws, size_t ws_size,
                              hipStream_t stream) {
  (void)in_sizes; (void)n_in; (void)out_size; (void)ws_size;
  const float* state = (const float*)d_in[0];
  const float* actions = (const float*)d_in[1];
  const float* h0 = (const float*)d_in[2];
  const float* c0 = (const float*)d_in[3];
  const float* w0 = (const float*)d_in[4];
  const float* b0 = (const float*)d_in[5];
  const float* w1 = (const float*)d_in[6];
  const float* b1 = (const float*)d_in[7];
  const float* w2 = (const float*)d_in[8];
  const float* b2 = (const float*)d_in[9];
  const float* w3 = (const float*)d_in[10];
  const float* b3 = (const float*)d_in[11];
  const float* wih = (const float*)d_in[12];
  const float* whh = (const float*)d_in[13];
  const float* bih = (const float*)d_in[14];
  const float* bhh = (const float*)d_in[15];
  const float* wq = (const float*)d_in[16];
  const float* bq = (const float*)d_in[17];
  const float* wk = (const float*)d_in[18];
  const float* bk = (const float*)d_in[19];
  const float* wv = (const float*)d_in[20];
  const float* bv = (const float*)d_in[21];
  const float* wout = (const float*)d_in[22];
  const float* bout = (const float*)d_in[23];

  char* ws = (char*)d_ws;
  size_t off = 0;
  auto take = [&](size_t bytes) {
    off = (off + 255) & ~(size_t)255;
    char* p = ws + off;
    off += bytes;
    return p;
  };
  u16* Xpad  = (u16*)take(131072UL * 192 * 2);
  u16* ping  = (u16*)take(32768UL * 512 * 2);
  u16* pong  = (u16*)take(32768UL * 512 * 2);
  u16* X4    = (u16*)take(131072UL * 256 * 2);
  u16* W0p   = (u16*)take(512UL * 192 * 2);
  u16* W1b   = (u16*)take(512UL * 512 * 2);
  u16* W2b   = (u16*)take(512UL * 512 * 2);
  u16* W3b   = (u16*)take(256UL * 512 * 2);
  u16* Wcat  = (u16*)take(1024UL * 512 * 2);
  u16* Wqkv  = (u16*)take(768UL * 256 * 2);
  u16* WoutB = (u16*)take(256UL * 256 * 2);
  float* bg   = (float*)take(1024UL * 4);
  float* bqkvp = (float*)take(768UL * 4);
  u16* kbuf  = (u16*)take(2UL * 512 * 256 * 2);
  u16* vtb   = (u16*)take(2UL * 256 * 512 * 2);
  unsigned* ctr = (unsigned*)take(256);

  hipMemsetAsync(ctr, 0, 256, stream);
  seqenc_prep<<<2048, 256, 0, stream>>>(state, actions, w0, w1, w2, w3, wih, whh, bih, bhh,
                                        wq, wk, wv, bq, bk, bv, wout,
                                        Xpad, Wcat, Wqkv, W0p, W1b, W2b, W3b, WoutB, bg, bqkvp);
  const int CM = 32768;
  for (int c = 0; c < 4; ++c) {
    const u16* a0 = Xpad + (size_t)c * CM * 192;
    u16* x4c = X4 + (size_t)c * CM * 256;
    seqenc_gemm<<<dim3(CM / 128, 4), 256, 0, stream>>>(a0, W0p, b0, ping, 192, 512, 1);
    seqenc_gemm<<<dim3(CM / 128, 4), 256, 0, stream>>>(ping, W1b, b1, pong, 512, 512, 1);
    seqenc_gemm<<<dim3(CM / 128, 4), 256, 0, stream>>>(pong, W2b, b2, ping, 512, 512, 1);
    seqenc_gemm<<<dim3(CM / 128, 2), 256, 0, stream>>>(ping, W3b, b3, x4c, 512, 256, 0);
  }
  seqenc_recurrent<<<32, 512, 0, stream>>>(X4, Wcat, bg, Wqkv, bqkvp, kbuf, vtb,
                                           WoutB, bout, h0, c0, (float*)d_out, ctr);
}